// Round 19
// baseline (344.486 us; speedup 1.0000x reference)
//
#include <hip/hip_runtime.h>
#include <hip/hip_bf16.h>
#include <math.h>

#define B_   2
#define S_   2048
#define HID_ 2048
#define NH_  16
#define NKV_ 4
#define HD_  128
#define NTOK (B_*S_)   // 4096

typedef __attribute__((ext_vector_type(8))) short s8v;            // 8 bf16 (MFMA A/B frag)
typedef __attribute__((ext_vector_type(8))) unsigned short u16x8;
typedef __attribute__((ext_vector_type(4))) float f32x4;

__device__ __forceinline__ float fexp2(float x) { return __builtin_amdgcn_exp2f(x); }

__device__ __forceinline__ unsigned short f2bf(float f) {
    unsigned int x = __builtin_bit_cast(unsigned int, f);
    x += 0x7fffu + ((x >> 16) & 1u);           // RNE
    return (unsigned short)(x >> 16);
}
__device__ __forceinline__ float bf2f(unsigned short h) {
    unsigned int x = ((unsigned int)h) << 16;
    return __builtin_bit_cast(float, x);
}

// async global->LDS, 16B per lane; LDS dest = wave-uniform base + lane*16
__device__ __forceinline__ void gload_lds16(const void* g, void* l) {
    __builtin_amdgcn_global_load_lds(
        (__attribute__((address_space(1))) void*)g,
        (__attribute__((address_space(3))) void*)l, 16, 0, 0);
}

// ---------------- conversions + RoPE table in ONE kernel ------------------------
__global__ __launch_bounds__(256) void prep_all(
    const float* __restrict__ hs, const float* __restrict__ wq,
    const float* __restrict__ wk, const float* __restrict__ wvp,
    const float* __restrict__ wo,
    unsigned short* __restrict__ hid_h, unsigned short* __restrict__ hid_l,
    unsigned short* __restrict__ wq_h,
    unsigned short* __restrict__ wk_h, unsigned short* __restrict__ wk_l,
    unsigned short* __restrict__ wv_h, unsigned short* __restrict__ wv_l,
    unsigned short* __restrict__ wo_h,
    float* __restrict__ ctab, float* __restrict__ stab)
{
    const int nHS = NTOK*HID_/8, nWQ = NH_*HD_*HID_/8, nWK = NKV_*HD_*HID_/8;
    const int nConv = nHS + nWQ + 2*nWK + nWQ;
    int i = blockIdx.x * 256 + threadIdx.x;
    if (i >= nConv) {
        int j = i - nConv;                        // rope table: pos*64 + d
        if (j >= S_*64) return;
        int d = j & 63, pos = j >> 6;
        double inv = pow(1.0e6, -(double)d / 64.0);
        double ang = (double)pos * inv;
        ctab[j] = (float)cos(ang);
        stab[j] = (float)sin(ang);
        return;
    }
    const float* src; unsigned short* dh; unsigned short* dl = nullptr; int off;
    if (i < nHS)                       { src = hs;  dh = hid_h; dl = hid_l; off = i; }
    else if (i < nHS+nWQ)              { src = wq;  dh = wq_h;  off = i-nHS; }
    else if (i < nHS+nWQ+nWK)          { src = wk;  dh = wk_h;  dl = wk_l; off = i-nHS-nWQ; }
    else if (i < nHS+nWQ+2*nWK)        { src = wvp; dh = wv_h;  dl = wv_l; off = i-nHS-nWQ-nWK; }
    else                               { src = wo;  dh = wo_h;  off = i-nHS-nWQ-2*nWK; }
    const float4* p = (const float4*)src + (size_t)off * 2;
    float4 a = p[0], b = p[1];
    float x[8] = {a.x,a.y,a.z,a.w,b.x,b.y,b.z,b.w};
    u16x8 oh, ol;
    #pragma unroll
    for (int j=0;j<8;j++) {
        unsigned short h = f2bf(x[j]);
        oh[j] = h;
        ol[j] = f2bf(x[j] - bf2f(h));
    }
    *((u16x8*)dh + off) = oh;
    if (dl) *((u16x8*)dl + off) = ol;
}

// ---------------- shared epilogue (NW=4 layout: wave rows m0+wv*32..+31) --------
template<int EPI>
__device__ __forceinline__ void gemm_epilogue(
    f32x4 (&acc)[2][8], const float* __restrict__ bias,
    float* __restrict__ C, unsigned short* __restrict__ Cb,
    const float* __restrict__ ctab, const float* __restrict__ stab,
    int N, int m0, int n0, bool kbranch)
{
    int lane = threadIdx.x & 63;
    int l15 = lane & 15;
    int wv = threadIdx.x >> 6;
    float bb[8];
    #pragma unroll
    for (int j=0;j<8;j++) bb[j] = (EPI==0 && !bias) ? 0.0f : bias[n0 + j*16 + l15];
    #pragma unroll
    for (int i=0;i<2;i++) {
        #pragma unroll
        for (int r=0;r<4;r++) {
            int row = m0 + wv*32 + i*16 + ((lane>>4)<<2) + r;
            if constexpr (EPI == 0) {
                #pragma unroll
                for (int j=0;j<8;j++)
                    C[(size_t)row*N + n0 + j*16 + l15] = acc[i][j][r] + bb[j];
            } else {
                float y[8];
                #pragma unroll
                for (int j=0;j<8;j++) y[j] = acc[i][j][r] + bb[j];
                if (EPI == 1 || kbranch) {           // RoPE
                    int pos = row & (S_-1);
                    #pragma unroll
                    for (int j=0;j<4;j++) {
                        int dm = j*16 + l15;
                        float cs = ctab[pos*64 + dm];
                        float sn = stab[pos*64 + dm];
                        float x1 = y[j], x2 = y[j+4];
                        y[j]   = x1*cs - x2*sn;
                        y[j+4] = x2*cs + x1*sn;
                    }
                }
                if constexpr (EPI == 1) {
                    const float sc = 0.1275174306f;   // log2(e)/sqrt(128)
                    #pragma unroll
                    for (int j=0;j<8;j++)
                        Cb[(size_t)row*N + n0 + j*16 + l15] = f2bf(y[j] * sc);
                } else {
                    float mn0 = fminf(fminf(y[0],y[1]), fminf(y[2],y[3]));
                    float mx0 = fmaxf(fmaxf(y[0],y[1]), fmaxf(y[2],y[3]));
                    float mn1 = fminf(fminf(y[4],y[5]), fminf(y[6],y[7]));
                    float mx1 = fmaxf(fmaxf(y[4],y[5]), fmaxf(y[6],y[7]));
                    #pragma unroll
                    for (int off=1; off<16; off<<=1) {
                        mn0 = fminf(mn0, __shfl_xor(mn0, off));
                        mx0 = fmaxf(mx0, __shfl_xor(mx0, off));
                        mn1 = fminf(mn1, __shfl_xor(mn1, off));
                        mx1 = fmaxf(mx1, __shfl_xor(mx1, off));
                    }
                    float s0 = (mx0 - mn0) / 15.0f; if (s0 == 0.0f) s0 = 1.0f;
                    float s1 = (mx1 - mn1) / 15.0f; if (s1 == 0.0f) s1 = 1.0f;
                    #pragma unroll
                    for (int j=0;j<4;j++) {
                        float q0 = rintf(fminf(fmaxf((y[j]  -mn0)/s0, 0.0f), 15.0f));
                        float q1 = rintf(fminf(fmaxf((y[j+4]-mn1)/s1, 0.0f), 15.0f));
                        Cb[(size_t)row*N + n0 + j*16     + l15] = f2bf(q0*s0 + mn0);
                        Cb[(size_t)row*N + n0 + (j+4)*16 + l15] = f2bf(q1*s1 + mn1);
                    }
                }
            }
        }
    }
}

#define NSTEP 64   // K = HID_ = 2048, BK = 32

// ---------------- 1-pass GEMM: 3-buffer LDS + counted vmcnt (R18-proven) --------
template<int EPI>
__device__ __forceinline__ void gemm_1p(
    unsigned short (*ls)[128*32],
    const unsigned short* __restrict__ A, const unsigned short* __restrict__ B,
    const float* __restrict__ bias,
    float* __restrict__ C, unsigned short* __restrict__ Cb,
    const float* __restrict__ ctab, const float* __restrict__ stab,
    int N, int K, int m0, int n0)
{
    int lane = threadIdx.x & 63;
    int l15 = lane & 15;
    int wv = threadIdx.x >> 6;
    int koff = (lane >> 4) << 3;

    auto stage = [&](int k0, int p) {
        #pragma unroll
        for (int j=0; j<2; j++) {
            int chunk = wv*2 + j;
            int e = chunk*512 + lane*8;
            int r = e >> 5, c = e & 31;
            gload_lds16(A + (size_t)(m0 + r)*K + k0 + c, ls[p*2+0] + chunk*512);
            gload_lds16(B + (size_t)(n0 + r)*K + k0 + c, ls[p*2+1] + chunk*512);
        }
    };

    f32x4 acc[2][8];
    for (int i=0;i<2;i++) for (int j=0;j<8;j++) acc[i][j] = (f32x4)0.0f;

    stage(0, 0);
    stage(32, 1);
    asm volatile("s_waitcnt vmcnt(4) lgkmcnt(0)" ::: "memory");  // stage(0) landed
    __builtin_amdgcn_s_barrier();

    for (int n = 0; n < NSTEP; n++) {
        int k0 = n*32;
        if (n + 2 < NSTEP) stage(k0 + 64, (n+2)%3);
        int cur = n % 3;
        s8v afh[2], bfh[8];
        #pragma unroll
        for (int i=0;i<2;i++)
            afh[i] = *(const s8v*)&ls[cur*2+0][(wv*32 + i*16 + l15)*32 + koff];
        #pragma unroll
        for (int j=0;j<8;j++)
            bfh[j] = *(const s8v*)&ls[cur*2+1][(j*16 + l15)*32 + koff];
        #pragma unroll
        for (int i=0;i<2;i++)
            #pragma unroll
            for (int j=0;j<8;j++)
                acc[i][j] = __builtin_amdgcn_mfma_f32_16x16x32_bf16(afh[i], bfh[j], acc[i][j], 0,0,0);
        if (n + 2 < NSTEP) {
            asm volatile("s_waitcnt vmcnt(4) lgkmcnt(0)" ::: "memory");
            __builtin_amdgcn_s_barrier();
        } else if (n + 1 < NSTEP) {
            asm volatile("s_waitcnt vmcnt(0) lgkmcnt(0)" ::: "memory");
            __builtin_amdgcn_s_barrier();
        }
    }
    gemm_epilogue<EPI>(acc, bias, C, Cb, ctab, stab, N, m0, n0, true);
}

// ---------------- 3-pass split GEMM (R14-proven): dbuf {Ah,Bh,Bl}; Al in regs ---
__device__ __forceinline__ void gemm_3p(
    unsigned short (*ls)[128*32],
    const unsigned short* __restrict__ Ah, const unsigned short* __restrict__ Al,
    const unsigned short* __restrict__ Bh, const unsigned short* __restrict__ Bl,
    const float* __restrict__ bias, unsigned short* __restrict__ Cb,
    const float* __restrict__ ctab, const float* __restrict__ stab,
    int N, int K, int m0, int n0, bool kbranch)
{
    int lane = threadIdx.x & 63;
    int l15 = lane & 15;
    int wv = threadIdx.x >> 6;
    int koff = (lane >> 4) << 3;

    auto stage = [&](int k0, int p) {
        #pragma unroll
        for (int j=0; j<2; j++) {
            int chunk = wv*2 + j;
            int e = chunk*512 + lane*8;
            int r = e >> 5, c = e & 31;
            gload_lds16(Ah + (size_t)(m0 + r)*K + k0 + c, ls[p*3+0] + chunk*512);
            gload_lds16(Bh + (size_t)(n0 + r)*K + k0 + c, ls[p*3+1] + chunk*512);
            gload_lds16(Bl + (size_t)(n0 + r)*K + k0 + c, ls[p*3+2] + chunk*512);
        }
    };
    auto loadAl = [&](int k0, uint4* alr) {
        #pragma unroll
        for (int i=0;i<2;i++) {
            int ar = wv*32 + i*16 + l15;
            alr[i] = *(const uint4*)(Al + (size_t)(m0 + ar)*K + k0 + koff);
        }
    };

    f32x4 acc[2][8];
    for (int i=0;i<2;i++) for (int j=0;j<8;j++) acc[i][j] = (f32x4)0.0f;

    uint4 alc[2], aln[2];
    stage(0, 0);
    loadAl(0, alc);
    __syncthreads();
    int cur = 0;
    for (int k0 = 0; k0 < K; k0 += 32) {
        bool more = k0 + 32 < K;
        if (more) { stage(k0 + 32, cur ^ 1); loadAl(k0 + 32, aln); }
        s8v afh[2], bfh[8], bfl[8];
        #pragma unroll
        for (int i=0;i<2;i++)
            afh[i] = *(const s8v*)&ls[cur*3+0][(wv*32 + i*16 + l15)*32 + koff];
        #pragma unroll
        for (int j=0;j<8;j++) {
            bfh[j] = *(const s8v*)&ls[cur*3+1][(j*16 + l15)*32 + koff];
            bfl[j] = *(const s8v*)&ls[cur*3+2][(j*16 + l15)*32 + koff];
        }
        #pragma unroll
        for (int i=0;i<2;i++) {
            s8v afl = __builtin_bit_cast(s8v, alc[i]);
            #pragma unroll
            for (int j=0;j<8;j++) {
                acc[i][j] = __builtin_amdgcn_mfma_f32_16x16x32_bf16(afh[i], bfh[j], acc[i][j], 0,0,0);
                acc[i][j] = __builtin_amdgcn_mfma_f32_16x16x32_bf16(afh[i], bfl[j], acc[i][j], 0,0,0);
                acc[i][j] = __builtin_amdgcn_mfma_f32_16x16x32_bf16(afl,    bfh[j], acc[i][j], 0,0,0);
            }
        }
        __syncthreads();                             // drains gll; publishes buf^1
        if (more) { alc[0] = aln[0]; alc[1] = aln[1]; }
        cur ^= 1;
    }
    gemm_epilogue<2>(acc, bias, nullptr, Cb, ctab, stab, N, m0, n0, kbranch);
}

// ---------------- fused QKV projection: XCD-swizzled with balanced work mix -----
__global__ __launch_bounds__(256) void qkv_gemm(
    const unsigned short* __restrict__ hid_h, const unsigned short* __restrict__ hid_l,
    const unsigned short* __restrict__ wq_h,
    const unsigned short* __restrict__ wk_h, const unsigned short* __restrict__ wk_l,
    const unsigned short* __restrict__ wv_h, const unsigned short* __restrict__ wv_l,
    const float* __restrict__ b_q, const float* __restrict__ b_k,
    const float* __restrict__ b_v,
    unsigned short* __restrict__ qb, unsigned short* __restrict__ kb,
    unsigned short* __restrict__ vb,
    const float* __restrict__ ctab, const float* __restrict__ stab)
{
    __shared__ unsigned short ls[6][128*32];        // 48KB
    int orig = blockIdx.x;
    int xcd = orig & 7, slot = orig >> 3;           // slot 0..95
    int bidx = (slot < 32) ? (xcd*32 + slot)        // KV items 0..255 (heavy, first)
                           : (256 + xcd*64 + (slot - 32));  // Q items 256..767
    if (bidx < 256) {
        int m0 = (bidx >> 3) << 7;
        int nt = bidx & 7;
        bool isK = nt < 4;
        gemm_3p(ls, hid_h, hid_l, isK ? wk_h : wv_h, isK ? wk_l : wv_l,
                isK ? b_k : b_v, isK ? kb : vb, ctab, stab,
                NKV_*HD_, HID_, m0, (nt & 3) << 7, isK);
    } else {
        int b2 = bidx - 256;                     // 0..511: Q, N=2048 (16 n-tiles)
        int m0 = (b2 >> 4) << 7;
        int n0 = (b2 & 15) << 7;
        gemm_1p<1>(ls, hid_h, wq_h, b_q, nullptr, qb, ctab, stab,
                   NH_*HD_, HID_, m0, n0);
    }
}

// ---------------- output projection (XCD-swizzled: 512 = 8 * 64, same-type) -----
__global__ __launch_bounds__(256) void wo_gemm(
    const unsigned short* __restrict__ ao, const unsigned short* __restrict__ wo_h,
    float* __restrict__ out)
{
    __shared__ unsigned short ls[6][128*32];        // 48KB: 3 bufs x {A,B}
    int orig = blockIdx.x;
    int bidx = (orig & 7) * 64 + (orig >> 3);
    int m0 = (bidx >> 4) << 7;
    int n0 = (bidx & 15) << 7;
    gemm_1p<0>(ls, ao, wo_h, nullptr, out, nullptr, nullptr, nullptr,
               HID_, HID_, m0, n0);
}

// ---------------- causal GQA flash attention, K-in-registers --------------------
// 4 waves, QBLK=64; block does qblk pair (qpair, 31-qpair) -> 33 tiles, uniform
// 512 blocks. K A-frags prefetched ONE TILE AHEAD into registers (ping-pong via
// 2x unrolled loop, no copies) -> no lsK, no bar1; LDS 32KB (lsV dbuf only).
// Barrier = raw s_barrier + lgkmcnt(0): K/V global prefetch stays in flight (T4).
__device__ __forceinline__ int vswz(int d) { return ((d ^ (d >> 3)) & 7) << 4; }

__global__ __launch_bounds__(256) void attn_kernel(
    const unsigned short* __restrict__ Qb,   // [NTOK][NH*HD], pre-scaled (log2e/sqrt(D))
    const unsigned short* __restrict__ Kb,   // [NTOK][NKV*HD]
    const unsigned short* __restrict__ Vb,
    unsigned short* __restrict__ Ob)         // [NTOK][NH*HD]
{
    __shared__ unsigned short lsV[2][128*64]; // [d][kv], elem kv at (kv ^ (sw(d)<<3))

    int tid = threadIdx.x, lane = tid & 63, wv = tid >> 6;   // wv 0..3
    int bidx  = blockIdx.x;
    int bh    = bidx & 31;
    int qpair = bidx >> 5;                     // 0..15
    int h     = bh & 15;
    int b     = bh >> 4;
    int hk    = h >> 2;
    size_t tokbase = (size_t)b * S_;
    int l15 = lane & 15;
    int g   = lane >> 4;
    int prow0 = g << 2;

    auto loadK = [&](int t, s8v* kf) {        // 16 coalesced b128 loads -> 64 VGPR
        #pragma unroll
        for (int nt=0; nt<4; nt++)
            #pragma unroll
            for (int kc=0; kc<4; kc++)
                kf[nt*4+kc] = *(const s8v*)(Kb +
                    ((tokbase + t*64 + nt*16 + l15)*NKV_ + hk)*HD_ + (g<<3) + kc*32);
    };
    auto loadV = [&](int t, uint4* vr) {
        #pragma unroll
        for (int it=0; it<4; it++) {
            int idx2 = it*4 + wv;
            int kvchunk = idx2 & 7, dhalf = idx2 >> 3;
            int e = lane & 7, gg = lane >> 3;
            vr[it] = *(const uint4*)(Vb +
                ((tokbase + t*64 + kvchunk*8 + e)*NKV_ + hk)*HD_ + dhalf*64 + gg*8);
        }
    };
    auto writeV = [&](uint4* vr, unsigned short* dstV) {
        #pragma unroll
        for (int it=0; it<4; it++) {
            int idx2 = it*4 + wv;
            int kvchunk = idx2 & 7, dhalf = idx2 >> 3;
            int e = lane & 7, gg = lane >> 3;
            uint4 w = vr[it];
            {   // step 4: 2-dword block swap
                unsigned int s0 = (e&4) ? w.x : w.z;
                unsigned int s1 = (e&4) ? w.y : w.w;
                unsigned int r0 = __shfl_xor(s0, 4);
                unsigned int r1 = __shfl_xor(s1, 4);
                if (e&4) { w.x = r0; w.y = r1; } else { w.z = r0; w.w = r1; }
            }
            {   // step 2: dword-level swap
                unsigned int s0 = (e&2) ? w.x : w.y;
                unsigned int s1 = (e&2) ? w.z : w.w;
                unsigned int r0 = __shfl_xor(s0, 2);
                unsigned int r1 = __shfl_xor(s1, 2);
                if (e&2) { w.x = r0; w.z = r1; } else { w.y = r0; w.w = r1; }
            }
            {   // step 1: u16-within-dword swap
                unsigned int r0 = __shfl_xor(w.x, 1);
                unsigned int r1 = __shfl_xor(w.y, 1);
                unsigned int r2 = __shfl_xor(w.z, 1);
                unsigned int r3 = __shfl_xor(w.w, 1);
                if (e&1) {
                    w.x = (w.x & 0xFFFF0000u) | (r0 >> 16);
                    w.y = (w.y & 0xFFFF0000u) | (r1 >> 16);
                    w.z = (w.z & 0xFFFF0000u) | (r2 >> 16);
                    w.w = (w.w & 0xFFFF0000u) | (r3 >> 16);
                } else {
                    w.x = (w.x & 0x0000FFFFu) | (r0 << 16);
                    w.y = (w.y & 0x0000FFFFu) | (r1 << 16);
                    w.z = (w.z & 0x0000FFFFu) | (r2 << 16);
                    w.w = (w.w & 0x0000FFFFu) | (r3 << 16);
                }
            }
            int d = dhalf*64 + gg*8 + e;
            int sw = (d ^ (d>>3)) & 7;
            int kvx = (kvchunk*8) ^ (sw<<3);
            *(uint4*)(dstV + d*64 + kvx) = w;
        }
    };

    for (int pi = 0; pi < 2; ++pi) {
        int qblk = pi ? (31 - qpair) : qpair;
        int q0   = qblk*64 + wv*16;
        int qlane = q0 + l15;                  // this lane's q row (swapped layout)

        s8v qf[4];
        {
            const unsigned short* qp = Qb + ((tokbase + qlane)*NH_ + h)*HD_ + (g<<3);
            #pragma unroll
            for (int kc=0; kc<4; kc++) qf[kc] = *(const s8v*)(qp + kc*32);
        }

        f32x4 o[8];
        #pragma unroll
        for (int i=0;i<8;i++) o[i] = (f32x4)0.0f;
        float m = -INFINITY, l = 0.0f;         // per-lane (one q row)

        int nt_end = qblk + 1;

        s8v kA[16], kB[16];
        uint4 vr[4];
        loadV(0, vr);
        loadK(0, kA);
        writeV(vr, &lsV[0][0]);
        asm volatile("s_waitcnt lgkmcnt(0)" ::: "memory");  // ds_writes visible
        __builtin_amdgcn_s_barrier();                       // K loads stay in flight

        auto body = [&](int t, s8v* kc_, s8v* kn_) {
            int cur = t & 1;
            bool more = (t+1 < nt_end);                // block-uniform
            bool needmask = (t*64 + 63) > q0;          // wave-uniform: diagonal region

            // ---- scores (swapped): S^T = K(64x128) @ Q^T, K from registers ----
            f32x4 s[4];
            __builtin_amdgcn_s_setprio(1);
            #pragma unroll
            for (int nt=0; nt<4; nt++) {
                s[nt] = (f32x4)0.0f;
                #pragma unroll
                for (int kc=0; kc<4; kc++)
                    s[nt] = __builtin_amdgcn_mfma_f32_16x16x32_bf16(kc_[nt*4+kc], qf[kc], s[nt], 0,0,0);
            }
            __builtin_amdgcn_s_setprio(0);
            if (more) {
                loadV(t+1, vr);        // issue next V loads (oldest in queue)
                loadK(t+1, kn_);       // issue next K loads (consumed next tile)
            }
            // ---- causal mask + online softmax (exp2), per-lane scalar state ----
            float mt = -INFINITY;
            if (needmask) {
                #pragma unroll
                for (int nt=0; nt<4; nt++)
                    #pragma unroll
                    for (int r=0;r<4;r++) {
                        int kvg = t*64 + nt*16 + (g<<2) + r;
                        float sv = s[nt][r];
                        if (kvg > qlane) sv = -1e30f;
                        s[nt][r] = sv;
                        mt = fmaxf(mt, sv);
                    }
            } else {
                #pragma unroll
                for (int nt=0; nt<4; nt++)
                    #pragma unroll
                    for (int r=0;r<4;r++) mt = fmaxf(mt, s[nt][r]);
            }
            mt = fmaxf(mt, __shfl_xor(mt, 16));
            mt = fmaxf(mt, __shfl_xor(mt, 32));
            // defer-max (T13): skip rescale if growth <= 8 (values <= 2^8)
            bool rescale = !__all(mt - m <= 8.0f);
            if (rescale) {
                float mn = fmaxf(m, mt);
                float scl = fexp2(m - mn);     // m=-inf first tile -> 0
                m = mn;
                l *= scl;
                #pragma unroll
                for (int r=0;r<4;r++) {
                    float sr = __shfl(scl, (prow0 + r) + (lane & 48));
                    #pragma unroll
                    for (int dt=0; dt<8; dt++) o[dt][r] *= sr;
                }
            }
            float p[4][4];
            float rs = 0.0f;
            #pragma unroll
            for (int nt=0; nt<4; nt++)
                #pragma unroll
                for (int r=0;r<4;r++) {
                    p[nt][r] = fexp2(s[nt][r] - m);
                    rs += p[nt][r];
                }
            rs += __shfl_xor(rs, 16);
            rs += __shfl_xor(rs, 32);
            l += rs;
            // ---- in-register P -> A-frag (cvt_pk + bpermute); no LDS ----
            s8v pa[2];
            unsigned int wpk[4][2];
            #pragma unroll
            for (int nt=0; nt<4; nt++)
                #pragma unroll
                for (int pr=0; pr<2; pr++) {
                    unsigned int w_;
                    asm("v_cvt_pk_bf16_f32 %0, %1, %2"
                        : "=v"(w_) : "v"(p[nt][2*pr]), "v"(p[nt][2*pr+1]));
                    wpk[nt][pr] = w_;
                }
            #pragma unroll
            for (int c=0;c<2;c++) {
                unsigned int dw[4];
                #pragma unroll
                for (int i=0;i<4;i++) {
                    int srcl = l15 + 16*(2*(g&1) + (i>>1));
                    unsigned int a0 = (unsigned int)__shfl((int)wpk[2*c+0][i&1], srcl);
                    unsigned int a1 = (unsigned int)__shfl((int)wpk[2*c+1][i&1], srcl);
                    dw[i] = (g>>1) ? a1 : a0;
                }
                uint4 t4; t4.x = dw[0]; t4.y = dw[1]; t4.z = dw[2]; t4.w = dw[3];
                pa[c] = __builtin_bit_cast(s8v, t4);
            }
            if (more) writeV(vr, &lsV[cur^1][0]);   // waits only V loads (K in flight)
            // ---- PV: O += P(16x64) @ V(64x128) ----
            __builtin_amdgcn_s_setprio(1);
            #pragma unroll
            for (int dt=0; dt<8; dt++) {
                int row = dt*16 + l15;
                #pragma unroll
                for (int c=0;c<2;c++) {
                    int byt = (c*64 + (g<<4)) ^ vswz(row);
                    s8v vfrag = *(const s8v*)&lsV[cur][row*64 + (byt >> 1)];
                    o[dt] = __builtin_amdgcn_mfma_f32_16x16x32_bf16(pa[c], vfrag, o[dt], 0,0,0);
                }
            }
            __builtin_amdgcn_s_setprio(0);
            asm volatile("s_waitcnt lgkmcnt(0)" ::: "memory");  // LDS r/w ordered
            __builtin_amdgcn_s_barrier();                       // K/V loads in flight
        };

        int t = 0;
        while (t < nt_end) {
            body(t, kA, kB); t++;
            if (t >= nt_end) break;
            body(t, kB, kA); t++;
        }
        // ---- epilogue: redistribute per-q l across lane groups ----
        #pragma unroll
        for (int r=0;r<4;r++) {
            float lr = __shfl(l, (prow0 + r) + (lane & 48));
            float inv = 1.0f / lr;
            int rq = q0 + prow0 + r;
            #pragma unroll
            for (int dt=0; dt<8; dt++) {
                int d = dt*16 + l15;
                Ob[((tokbase + rq)*NH_ + h)*HD_ + d] = f2bf(o[dt][r] * inv);
            }
        }
    }
}

// ---------------- host launcher --------------------------------------------------
extern "C" void kernel_launch(void* const* d_in, const int* in_sizes, int n_in,
                              void* d_out, int out_size, void* d_ws, size_t ws_size,
                              hipStream_t stream) {
    const float* hs  = (const float*)d_in[0];
    const float* w_q = (const float*)d_in[1];
    const float* b_q = (const float*)d_in[2];
    const float* w_k = (const float*)d_in[3];
    const float* b_k = (const float*)d_in[4];
    const float* w_v = (const float*)d_in[5];
    const float* b_v = (const float*)d_in[6];
    const float* w_o = (const float*)d_in[7];
    float* out = (float*)d_out;

    char* p = (char*)d_ws;
    auto alloc = [&](size_t bytes) { char* r = p; p += (bytes + 255) & ~(size_t)255; return r; };
    unsigned short* hid_h = (unsigned short*)alloc((size_t)NTOK*HID_*2);
    unsigned short* hid_l = (unsigned short*)alloc((size_t)NTOK*HID_*2);
    unsigned short* wq_h  = (unsigned short*)alloc((size_t)NH_*HD_*HID_*2);
    unsigned short* wk_h  = (unsigned short*)alloc((size_t)NKV_*HD_*HID_*2);
    unsigned short* wk_l  = (unsigned short*)alloc((size_t)NKV_*HD_*HID_*2);
    unsigned short* wv_h  = (unsigned short*)alloc((size_t)NKV_*HD_*HID_*2);
    unsigned short* wv_l  = (unsigned short*)alloc((size_t)NKV_*HD_*HID_*2);
    unsigned short* wo_h  = (unsigned short*)alloc((size_t)HID_*NH_*HD_*2);
    unsigned short* qb = (unsigned short*)alloc((size_t)NTOK*NH_*HD_*2);
    unsigned short* kb = (unsigned short*)alloc((size_t)NTOK*NKV_*HD_*2);
    unsigned short* vb = (unsigned short*)alloc((size_t)NTOK*NKV_*HD_*2);
    unsigned short* ao = (unsigned short*)alloc((size_t)NTOK*NH_*HD_*2);
    float* ctab = (float*)alloc((size_t)S_*64*4);
    float* stab = (float*)alloc((size_t)S_*64*4);

    // conversions + rope table (1 launch)
    {
        int n8 = NTOK*HID_/8 + NH_*HD_*HID_/8 + 2*(NKV_*HD_*HID_/8) + HID_*NH_*HD_/8;
        int total = n8 + S_*64;
        prep_all<<<(total + 255)/256, 256, 0, stream>>>(
            hs, w_q, w_k, w_v, w_o, hid_h, hid_l, wq_h, wk_h, wk_l, wv_h, wv_l, wo_h,
            ctab, stab);
    }

    // fused Q + KV projections, balanced XCD swizzle: 768 blocks, one launch
    qkv_gemm<<<768, 256, 0, stream>>>(
        hid_h, hid_l, wq_h, wk_h, wk_l, wv_h, wv_l,
        b_q, b_k, b_v, qb, kb, vb, ctab, stab);

    // causal GQA attention: 512 uniform blocks x 4 waves, K-in-regs, 32KB LDS
    attn_kernel<<<B_*NH_*16, 256, 0, stream>>>(qb, kb, vb, ao);

    // output projection (no bias), XCD-swizzled, 1-pass bf16 -> fp32 d_out
    wo_gemm<<<(NTOK/128)*(HID_/128), 256, 0, stream>>>(ao, wo_h, out);
}

// Round 20
// 277.322 us; speedup vs baseline: 1.2422x; 1.2422x over previous
//
#include <hip/hip_runtime.h>
#include <hip/hip_bf16.h>
#include <math.h>

#define B_   2
#define S_   2048
#define HID_ 2048
#define NH_  16
#define NKV_ 4
#define HD_  128
#define NTOK (B_*S_)   // 4096

typedef __attribute__((ext_vector_type(8))) short s8v;            // 8 bf16 (MFMA A/B frag)
typedef __attribute__((ext_vector_type(8))) unsigned short u16x8;
typedef __attribute__((ext_vector_type(4))) float f32x4;

__device__ __forceinline__ float fexp2(float x) { return __builtin_amdgcn_exp2f(x); }

__device__ __forceinline__ unsigned short f2bf(float f) {
    unsigned int x = __builtin_bit_cast(unsigned int, f);
    x += 0x7fffu + ((x >> 16) & 1u);           // RNE
    return (unsigned short)(x >> 16);
}
__device__ __forceinline__ float bf2f(unsigned short h) {
    unsigned int x = ((unsigned int)h) << 16;
    return __builtin_bit_cast(float, x);
}

// async global->LDS, 16B per lane; LDS dest = wave-uniform base + lane*16
__device__ __forceinline__ void gload_lds16(const void* g, void* l) {
    __builtin_amdgcn_global_load_lds(
        (__attribute__((address_space(1))) void*)g,
        (__attribute__((address_space(3))) void*)l, 16, 0, 0);
}

// ---------------- conversions + RoPE table in ONE kernel ------------------------
__global__ __launch_bounds__(256) void prep_all(
    const float* __restrict__ hs, const float* __restrict__ wq,
    const float* __restrict__ wk, const float* __restrict__ wvp,
    const float* __restrict__ wo,
    unsigned short* __restrict__ hid_h, unsigned short* __restrict__ hid_l,
    unsigned short* __restrict__ wq_h,
    unsigned short* __restrict__ wk_h, unsigned short* __restrict__ wk_l,
    unsigned short* __restrict__ wv_h, unsigned short* __restrict__ wv_l,
    unsigned short* __restrict__ wo_h,
    float* __restrict__ ctab, float* __restrict__ stab)
{
    const int nHS = NTOK*HID_/8, nWQ = NH_*HD_*HID_/8, nWK = NKV_*HD_*HID_/8;
    const int nConv = nHS + nWQ + 2*nWK + nWQ;
    int i = blockIdx.x * 256 + threadIdx.x;
    if (i >= nConv) {
        int j = i - nConv;                        // rope table: pos*64 + d
        if (j >= S_*64) return;
        int d = j & 63, pos = j >> 6;
        double inv = pow(1.0e6, -(double)d / 64.0);
        double ang = (double)pos * inv;
        ctab[j] = (float)cos(ang);
        stab[j] = (float)sin(ang);
        return;
    }
    const float* src; unsigned short* dh; unsigned short* dl = nullptr; int off;
    if (i < nHS)                       { src = hs;  dh = hid_h; dl = hid_l; off = i; }
    else if (i < nHS+nWQ)              { src = wq;  dh = wq_h;  off = i-nHS; }
    else if (i < nHS+nWQ+nWK)          { src = wk;  dh = wk_h;  dl = wk_l; off = i-nHS-nWQ; }
    else if (i < nHS+nWQ+2*nWK)        { src = wvp; dh = wv_h;  dl = wv_l; off = i-nHS-nWQ-nWK; }
    else                               { src = wo;  dh = wo_h;  off = i-nHS-nWQ-2*nWK; }
    const float4* p = (const float4*)src + (size_t)off * 2;
    float4 a = p[0], b = p[1];
    float x[8] = {a.x,a.y,a.z,a.w,b.x,b.y,b.z,b.w};
    u16x8 oh, ol;
    #pragma unroll
    for (int j=0;j<8;j++) {
        unsigned short h = f2bf(x[j]);
        oh[j] = h;
        ol[j] = f2bf(x[j] - bf2f(h));
    }
    *((u16x8*)dh + off) = oh;
    if (dl) *((u16x8*)dl + off) = ol;
}

// ---------------- shared epilogue (NW=4 layout: wave rows m0+wv*32..+31) --------
// EPI: 0 = fp32 +bias; 1 = Q rope+log2e/sqrt(D)->bf16; 2 = KV (+rope if kbranch)+quant->bf16
template<int EPI>
__device__ __forceinline__ void gemm_epilogue(
    f32x4 (&acc)[2][8], const float* __restrict__ bias,
    float* __restrict__ C, unsigned short* __restrict__ Cb,
    const float* __restrict__ ctab, const float* __restrict__ stab,
    int N, int m0, int n0, bool kbranch)
{
    int lane = threadIdx.x & 63;
    int l15 = lane & 15;
    int wv = threadIdx.x >> 6;
    float bb[8];
    #pragma unroll
    for (int j=0;j<8;j++) bb[j] = (EPI==0 && !bias) ? 0.0f : bias[n0 + j*16 + l15];
    #pragma unroll
    for (int i=0;i<2;i++) {
        #pragma unroll
        for (int r=0;r<4;r++) {
            int row = m0 + wv*32 + i*16 + ((lane>>4)<<2) + r;
            if constexpr (EPI == 0) {
                #pragma unroll
                for (int j=0;j<8;j++)
                    C[(size_t)row*N + n0 + j*16 + l15] = acc[i][j][r] + bb[j];
            } else {
                float y[8];
                #pragma unroll
                for (int j=0;j<8;j++) y[j] = acc[i][j][r] + bb[j];
                if (EPI == 1 || kbranch) {           // RoPE
                    int pos = row & (S_-1);
                    #pragma unroll
                    for (int j=0;j<4;j++) {
                        int dm = j*16 + l15;
                        float cs = ctab[pos*64 + dm];
                        float sn = stab[pos*64 + dm];
                        float x1 = y[j], x2 = y[j+4];
                        y[j]   = x1*cs - x2*sn;
                        y[j+4] = x2*cs + x1*sn;
                    }
                }
                if constexpr (EPI == 1) {
                    const float sc = 0.1275174306f;   // log2(e)/sqrt(128)
                    #pragma unroll
                    for (int j=0;j<8;j++)
                        Cb[(size_t)row*N + n0 + j*16 + l15] = f2bf(y[j] * sc);
                } else {
                    float mn0 = fminf(fminf(y[0],y[1]), fminf(y[2],y[3]));
                    float mx0 = fmaxf(fmaxf(y[0],y[1]), fmaxf(y[2],y[3]));
                    float mn1 = fminf(fminf(y[4],y[5]), fminf(y[6],y[7]));
                    float mx1 = fmaxf(fmaxf(y[4],y[5]), fmaxf(y[6],y[7]));
                    #pragma unroll
                    for (int off=1; off<16; off<<=1) {
                        mn0 = fminf(mn0, __shfl_xor(mn0, off));
                        mx0 = fmaxf(mx0, __shfl_xor(mx0, off));
                        mn1 = fminf(mn1, __shfl_xor(mn1, off));
                        mx1 = fmaxf(mx1, __shfl_xor(mx1, off));
                    }
                    float s0 = (mx0 - mn0) / 15.0f; if (s0 == 0.0f) s0 = 1.0f;
                    float s1 = (mx1 - mn1) / 15.0f; if (s1 == 0.0f) s1 = 1.0f;
                    #pragma unroll
                    for (int j=0;j<4;j++) {
                        float q0 = rintf(fminf(fmaxf((y[j]  -mn0)/s0, 0.0f), 15.0f));
                        float q1 = rintf(fminf(fmaxf((y[j+4]-mn1)/s1, 0.0f), 15.0f));
                        Cb[(size_t)row*N + n0 + j*16     + l15] = f2bf(q0*s0 + mn0);
                        Cb[(size_t)row*N + n0 + (j+4)*16 + l15] = f2bf(q1*s1 + mn1);
                    }
                }
            }
        }
    }
}

#define NSTEP 64   // K = HID_ = 2048, BK = 32

// ---------------- 1-pass GEMM: 3-buffer LDS + counted vmcnt + raw s_barrier -----
// Region n issues 4 gll into buf (n+2)%3; end-of-region s_waitcnt vmcnt(4) leaves
// this region's 4 in flight -> stage(n+1)'s writes complete; ~2 iters of cover.
template<int EPI>
__device__ __forceinline__ void gemm_1p(
    unsigned short (*ls)[128*32],
    const unsigned short* __restrict__ A, const unsigned short* __restrict__ B,
    const float* __restrict__ bias,
    float* __restrict__ C, unsigned short* __restrict__ Cb,
    const float* __restrict__ ctab, const float* __restrict__ stab,
    int N, int K, int m0, int n0)
{
    int lane = threadIdx.x & 63;
    int l15 = lane & 15;
    int wv = threadIdx.x >> 6;
    int koff = (lane >> 4) << 3;

    auto stage = [&](int k0, int p) {
        #pragma unroll
        for (int j=0; j<2; j++) {
            int chunk = wv*2 + j;
            int e = chunk*512 + lane*8;
            int r = e >> 5, c = e & 31;
            gload_lds16(A + (size_t)(m0 + r)*K + k0 + c, ls[p*2+0] + chunk*512);
            gload_lds16(B + (size_t)(n0 + r)*K + k0 + c, ls[p*2+1] + chunk*512);
        }
    };

    f32x4 acc[2][8];
    for (int i=0;i<2;i++) for (int j=0;j<8;j++) acc[i][j] = (f32x4)0.0f;

    stage(0, 0);
    stage(32, 1);
    asm volatile("s_waitcnt vmcnt(4) lgkmcnt(0)" ::: "memory");  // stage(0) landed
    __builtin_amdgcn_s_barrier();

    for (int n = 0; n < NSTEP; n++) {
        int k0 = n*32;
        if (n + 2 < NSTEP) stage(k0 + 64, (n+2)%3);
        int cur = n % 3;
        s8v afh[2], bfh[8];
        #pragma unroll
        for (int i=0;i<2;i++)
            afh[i] = *(const s8v*)&ls[cur*2+0][(wv*32 + i*16 + l15)*32 + koff];
        #pragma unroll
        for (int j=0;j<8;j++)
            bfh[j] = *(const s8v*)&ls[cur*2+1][(j*16 + l15)*32 + koff];
        #pragma unroll
        for (int i=0;i<2;i++)
            #pragma unroll
            for (int j=0;j<8;j++)
                acc[i][j] = __builtin_amdgcn_mfma_f32_16x16x32_bf16(afh[i], bfh[j], acc[i][j], 0,0,0);
        if (n + 2 < NSTEP) {
            asm volatile("s_waitcnt vmcnt(4) lgkmcnt(0)" ::: "memory");
            __builtin_amdgcn_s_barrier();
        } else if (n + 1 < NSTEP) {
            asm volatile("s_waitcnt vmcnt(0) lgkmcnt(0)" ::: "memory");
            __builtin_amdgcn_s_barrier();
        }
    }
    gemm_epilogue<EPI>(acc, bias, C, Cb, ctab, stab, N, m0, n0, true);
}

// ---------------- 3-pass split GEMM (R14-proven): dbuf {Ah,Bh,Bl}; Al in regs ---
__device__ __forceinline__ void gemm_3p(
    unsigned short (*ls)[128*32],
    const unsigned short* __restrict__ Ah, const unsigned short* __restrict__ Al,
    const unsigned short* __restrict__ Bh, const unsigned short* __restrict__ Bl,
    const float* __restrict__ bias, unsigned short* __restrict__ Cb,
    const float* __restrict__ ctab, const float* __restrict__ stab,
    int N, int K, int m0, int n0, bool kbranch)
{
    int lane = threadIdx.x & 63;
    int l15 = lane & 15;
    int wv = threadIdx.x >> 6;
    int koff = (lane >> 4) << 3;

    auto stage = [&](int k0, int p) {
        #pragma unroll
        for (int j=0; j<2; j++) {
            int chunk = wv*2 + j;
            int e = chunk*512 + lane*8;
            int r = e >> 5, c = e & 31;
            gload_lds16(Ah + (size_t)(m0 + r)*K + k0 + c, ls[p*3+0] + chunk*512);
            gload_lds16(Bh + (size_t)(n0 + r)*K + k0 + c, ls[p*3+1] + chunk*512);
            gload_lds16(Bl + (size_t)(n0 + r)*K + k0 + c, ls[p*3+2] + chunk*512);
        }
    };
    auto loadAl = [&](int k0, uint4* alr) {
        #pragma unroll
        for (int i=0;i<2;i++) {
            int ar = wv*32 + i*16 + l15;
            alr[i] = *(const uint4*)(Al + (size_t)(m0 + ar)*K + k0 + koff);
        }
    };

    f32x4 acc[2][8];
    for (int i=0;i<2;i++) for (int j=0;j<8;j++) acc[i][j] = (f32x4)0.0f;

    uint4 alc[2], aln[2];
    stage(0, 0);
    loadAl(0, alc);
    __syncthreads();
    int cur = 0;
    for (int k0 = 0; k0 < K; k0 += 32) {
        bool more = k0 + 32 < K;
        if (more) { stage(k0 + 32, cur ^ 1); loadAl(k0 + 32, aln); }
        s8v afh[2], bfh[8], bfl[8];
        #pragma unroll
        for (int i=0;i<2;i++)
            afh[i] = *(const s8v*)&ls[cur*3+0][(wv*32 + i*16 + l15)*32 + koff];
        #pragma unroll
        for (int j=0;j<8;j++) {
            bfh[j] = *(const s8v*)&ls[cur*3+1][(j*16 + l15)*32 + koff];
            bfl[j] = *(const s8v*)&ls[cur*3+2][(j*16 + l15)*32 + koff];
        }
        #pragma unroll
        for (int i=0;i<2;i++) {
            s8v afl = __builtin_bit_cast(s8v, alc[i]);
            #pragma unroll
            for (int j=0;j<8;j++) {
                acc[i][j] = __builtin_amdgcn_mfma_f32_16x16x32_bf16(afh[i], bfh[j], acc[i][j], 0,0,0);
                acc[i][j] = __builtin_amdgcn_mfma_f32_16x16x32_bf16(afh[i], bfl[j], acc[i][j], 0,0,0);
                acc[i][j] = __builtin_amdgcn_mfma_f32_16x16x32_bf16(afl,    bfh[j], acc[i][j], 0,0,0);
            }
        }
        __syncthreads();                             // drains gll; publishes buf^1
        if (more) { alc[0] = aln[0]; alc[1] = aln[1]; }
        cur ^= 1;
    }
    gemm_epilogue<2>(acc, bias, nullptr, Cb, ctab, stab, N, m0, n0, kbranch);
}

// ---------------- fused QKV projection: XCD-swizzled with balanced work mix -----
// Each XCD x gets KV items x*32..x*32+31 AND Q items 256+x*64..+63 (same mix per
// XCD -> no cross-XCD imbalance). Dispatch order = KV slots first (heavy-first).
__global__ __launch_bounds__(256) void qkv_gemm(
    const unsigned short* __restrict__ hid_h, const unsigned short* __restrict__ hid_l,
    const unsigned short* __restrict__ wq_h,
    const unsigned short* __restrict__ wk_h, const unsigned short* __restrict__ wk_l,
    const unsigned short* __restrict__ wv_h, const unsigned short* __restrict__ wv_l,
    const float* __restrict__ b_q, const float* __restrict__ b_k,
    const float* __restrict__ b_v,
    unsigned short* __restrict__ qb, unsigned short* __restrict__ kb,
    unsigned short* __restrict__ vb,
    const float* __restrict__ ctab, const float* __restrict__ stab)
{
    __shared__ unsigned short ls[6][128*32];        // 48KB
    int orig = blockIdx.x;
    int xcd = orig & 7, slot = orig >> 3;           // slot 0..95
    int bidx = (slot < 32) ? (xcd*32 + slot)        // KV items 0..255 (heavy, first)
                           : (256 + xcd*64 + (slot - 32));  // Q items 256..767
    if (bidx < 256) {
        int m0 = (bidx >> 3) << 7;
        int nt = bidx & 7;
        bool isK = nt < 4;
        gemm_3p(ls, hid_h, hid_l, isK ? wk_h : wv_h, isK ? wk_l : wv_l,
                isK ? b_k : b_v, isK ? kb : vb, ctab, stab,
                NKV_*HD_, HID_, m0, (nt & 3) << 7, isK);
    } else {
        int b2 = bidx - 256;                     // 0..511: Q, N=2048 (16 n-tiles)
        int m0 = (b2 >> 4) << 7;
        int n0 = (b2 & 15) << 7;
        gemm_1p<1>(ls, hid_h, wq_h, b_q, nullptr, qb, ctab, stab,
                   NH_*HD_, HID_, m0, n0);
    }
}

// ---------------- output projection (XCD-swizzled: 512 = 8 * 64, same-type) -----
__global__ __launch_bounds__(256) void wo_gemm(
    const unsigned short* __restrict__ ao, const unsigned short* __restrict__ wo_h,
    float* __restrict__ out)
{
    __shared__ unsigned short ls[6][128*32];        // 48KB: 3 bufs x {A,B}
    int orig = blockIdx.x;
    int bidx = (orig & 7) * 64 + (orig >> 3);
    int m0 = (bidx >> 4) << 7;
    int n0 = (bidx & 15) << 7;
    gemm_1p<0>(ls, ao, wo_h, nullptr, out, nullptr, nullptr, nullptr,
               HID_, HID_, m0, n0);
}

// ---------------- causal GQA flash attention (R10/R18 proven) -------------------
// 4 waves, QBLK=64; block does qblk pair (qpair, 31-qpair) -> 33 tiles each =
// uniform 512 blocks; 48KB LDS. Swapped scores: lane holds ONE q row.
// In-register P (cvt_pk + bpermute). K single-buffer gll; V dbuf reg-transpose.
__device__ __forceinline__ int vswz(int d) { return ((d ^ (d >> 3)) & 7) << 4; }

__global__ __launch_bounds__(256) void attn_kernel(
    const unsigned short* __restrict__ Qb,   // [NTOK][NH*HD], pre-scaled (log2e/sqrt(D))
    const unsigned short* __restrict__ Kb,   // [NTOK][NKV*HD]
    const unsigned short* __restrict__ Vb,
    unsigned short* __restrict__ Ob)         // [NTOK][NH*HD]
{
    __shared__ unsigned short lsK[64*128];    // [kv][d-chunks], slot c8' holds chunk c8'^(r&7)
    __shared__ unsigned short lsV[2][128*64]; // [d][kv], elem kv at (kv ^ (sw(d)<<3))

    int tid = threadIdx.x, lane = tid & 63, wv = tid >> 6;   // wv 0..3
    int bidx  = blockIdx.x;
    int bh    = bidx & 31;
    int qpair = bidx >> 5;                     // 0..15
    int h     = bh & 15;
    int b     = bh >> 4;
    int hk    = h >> 2;
    size_t tokbase = (size_t)b * S_;
    int l15 = lane & 15;
    int g   = lane >> 4;
    int prow0 = g << 2;

    auto stageK = [&](int t) {
        #pragma unroll
        for (int it=0; it<4; it++) {
            int mI = it*4 + wv;
            int r  = mI*4 + (lane>>4);
            int c8 = (lane & 15) ^ (r & 7);
            gload_lds16(Kb + ((tokbase + t*64 + r)*NKV_ + hk)*HD_ + (c8<<3), &lsK[mI*512]);
        }
    };
    auto loadV = [&](int t, uint4* vr) {
        #pragma unroll
        for (int it=0; it<4; it++) {
            int idx2 = it*4 + wv;
            int kvchunk = idx2 & 7, dhalf = idx2 >> 3;
            int e = lane & 7, gg = lane >> 3;
            vr[it] = *(const uint4*)(Vb +
                ((tokbase + t*64 + kvchunk*8 + e)*NKV_ + hk)*HD_ + dhalf*64 + gg*8);
        }
    };
    auto writeV = [&](uint4* vr, unsigned short* dstV) {
        #pragma unroll
        for (int it=0; it<4; it++) {
            int idx2 = it*4 + wv;
            int kvchunk = idx2 & 7, dhalf = idx2 >> 3;
            int e = lane & 7, gg = lane >> 3;
            uint4 w = vr[it];
            {   // step 4: 2-dword block swap
                unsigned int s0 = (e&4) ? w.x : w.z;
                unsigned int s1 = (e&4) ? w.y : w.w;
                unsigned int r0 = __shfl_xor(s0, 4);
                unsigned int r1 = __shfl_xor(s1, 4);
                if (e&4) { w.x = r0; w.y = r1; } else { w.z = r0; w.w = r1; }
            }
            {   // step 2: dword-level swap
                unsigned int s0 = (e&2) ? w.x : w.y;
                unsigned int s1 = (e&2) ? w.z : w.w;
                unsigned int r0 = __shfl_xor(s0, 2);
                unsigned int r1 = __shfl_xor(s1, 2);
                if (e&2) { w.x = r0; w.z = r1; } else { w.y = r0; w.w = r1; }
            }
            {   // step 1: u16-within-dword swap
                unsigned int r0 = __shfl_xor(w.x, 1);
                unsigned int r1 = __shfl_xor(w.y, 1);
                unsigned int r2 = __shfl_xor(w.z, 1);
                unsigned int r3 = __shfl_xor(w.w, 1);
                if (e&1) {
                    w.x = (w.x & 0xFFFF0000u) | (r0 >> 16);
                    w.y = (w.y & 0xFFFF0000u) | (r1 >> 16);
                    w.z = (w.z & 0xFFFF0000u) | (r2 >> 16);
                    w.w = (w.w & 0xFFFF0000u) | (r3 >> 16);
                } else {
                    w.x = (w.x & 0x0000FFFFu) | (r0 << 16);
                    w.y = (w.y & 0x0000FFFFu) | (r1 << 16);
                    w.z = (w.z & 0x0000FFFFu) | (r2 << 16);
                    w.w = (w.w & 0x0000FFFFu) | (r3 << 16);
                }
            }
            int d = dhalf*64 + gg*8 + e;
            int sw = (d ^ (d>>3)) & 7;
            int kvx = (kvchunk*8) ^ (sw<<3);
            *(uint4*)(dstV + d*64 + kvx) = w;
        }
    };

    for (int pi = 0; pi < 2; ++pi) {
        int qblk = pi ? (31 - qpair) : qpair;
        int q0   = qblk*64 + wv*16;
        int qlane = q0 + l15;                  // this lane's q row (swapped layout)

        s8v qf[4];
        {
            const unsigned short* qp = Qb + ((tokbase + qlane)*NH_ + h)*HD_ + (g<<3);
            #pragma unroll
            for (int kc=0; kc<4; kc++) qf[kc] = *(const s8v*)(qp + kc*32);
        }

        f32x4 o[8];
        #pragma unroll
        for (int i=0;i<8;i++) o[i] = (f32x4)0.0f;
        float m = -INFINITY, l = 0.0f;         // per-lane (one q row)

        int nt_end = qblk + 1;

        uint4 vr[4];
        loadV(0, vr);                 // loads first (oldest in vm queue)
        stageK(0);                    // gll after -> writeV wait leaves it in flight
        writeV(vr, &lsV[0][0]);
        __syncthreads();              // drains gll: lsK/lsV[0] ready

        for (int t=0; t<nt_end; t++) {
            int cur = t & 1;
            bool more = (t+1 < nt_end);                // block-uniform
            bool fullmask = (q0 + 15) < t*64;          // wave-uniform: tile fully masked
            bool needmask = (t*64 + 63) > q0;          // wave-uniform: diagonal region

            // ---- scores (swapped): S^T = K(64x128) @ Q^T -> lane q = qlane ----
            f32x4 s[4];
            if (!fullmask) {
                __builtin_amdgcn_s_setprio(1);
                #pragma unroll
                for (int nt=0; nt<4; nt++) {
                    s[nt] = (f32x4)0.0f;
                    int row = nt*16 + l15;
                    #pragma unroll
                    for (int kc=0; kc<4; kc++) {
                        int byt = (kc*64 + (g<<4)) ^ ((row & 7) << 4);
                        s8v kfrag = *(const s8v*)&lsK[row*128 + (byt >> 1)];
                        s[nt] = __builtin_amdgcn_mfma_f32_16x16x32_bf16(kfrag, qf[kc], s[nt], 0,0,0);
                    }
                }
                __builtin_amdgcn_s_setprio(0);
            }
            if (more) {
                __syncthreads();       // bar1: all QK reads of lsK done (vm queue empty)
                loadV(t+1, vr);        // issue next V loads (regs)
                stageK(t+1);           // issue next K gll into lsK
            }
            s8v pa[2];
            if (!fullmask) {
                // ---- causal mask + online softmax (exp2), per-lane scalar state ----
                float mt = -INFINITY;
                if (needmask) {
                    #pragma unroll
                    for (int nt=0; nt<4; nt++)
                        #pragma unroll
                        for (int r=0;r<4;r++) {
                            int kvg = t*64 + nt*16 + (g<<2) + r;
                            float sv = s[nt][r];
                            if (kvg > qlane) sv = -1e30f;
                            s[nt][r] = sv;
                            mt = fmaxf(mt, sv);
                        }
                } else {
                    #pragma unroll
                    for (int nt=0; nt<4; nt++)
                        #pragma unroll
                        for (int r=0;r<4;r++) mt = fmaxf(mt, s[nt][r]);
                }
                mt = fmaxf(mt, __shfl_xor(mt, 16));
                mt = fmaxf(mt, __shfl_xor(mt, 32));
                // defer-max (T13): skip rescale if growth <= 8 (values <= 2^8)
                bool rescale = !__all(mt - m <= 8.0f);
                if (rescale) {
                    float mn = fmaxf(m, mt);
                    float scl = fexp2(m - mn);     // m=-inf first tile -> 0
                    m = mn;
                    l *= scl;
                    #pragma unroll
                    for (int r=0;r<4;r++) {
                        float sr = __shfl(scl, (prow0 + r) + (lane & 48));
                        #pragma unroll
                        for (int dt=0; dt<8; dt++) o[dt][r] *= sr;
                    }
                }
                float p[4][4];
                float rs = 0.0f;
                #pragma unroll
                for (int nt=0; nt<4; nt++)
                    #pragma unroll
                    for (int r=0;r<4;r++) {
                        p[nt][r] = fexp2(s[nt][r] - m);
                        rs += p[nt][r];
                    }
                rs += __shfl_xor(rs, 16);
                rs += __shfl_xor(rs, 32);
                l += rs;
                // ---- in-register P -> A-frag (cvt_pk + bpermute); no LDS ----
                unsigned int wpk[4][2];
                #pragma unroll
                for (int nt=0; nt<4; nt++)
                    #pragma unroll
                    for (int pr=0; pr<2; pr++) {
                        unsigned int w_;
                        asm("v_cvt_pk_bf16_f32 %0, %1, %2"
                            : "=v"(w_) : "v"(p[nt][2*pr]), "v"(p[nt][2*pr+1]));
                        wpk[nt][pr] = w_;
                    }
                #pragma unroll
                for (int c=0;c<2;c++) {
                    unsigned int dw[4];
                    #pragma unroll
                    for (int i=0;i<4;i++) {
                        int srcl = l15 + 16*(2*(g&1) + (i>>1));
                        unsigned int a0 = (unsigned int)__shfl((int)wpk[2*c+0][i&1], srcl);
                        unsigned int a1 = (unsigned int)__shfl((int)wpk[2*c+1][i&1], srcl);
                        dw[i] = (g>>1) ? a1 : a0;
                    }
                    uint4 t4; t4.x = dw[0]; t4.y = dw[1]; t4.z = dw[2]; t4.w = dw[3];
                    pa[c] = __builtin_bit_cast(s8v, t4);
                }
            }
            if (more) writeV(vr, &lsV[cur^1][0]);   // waits only V loads (gll in flight)
            if (!fullmask) {
                // ---- PV: O += P(16x64) @ V(64x128) ----
                __builtin_amdgcn_s_setprio(1);
                #pragma unroll
                for (int dt=0; dt<8; dt++) {
                    int row = dt*16 + l15;
                    #pragma unroll
                    for (int c=0;c<2;c++) {
                        int byt = (c*64 + (g<<4)) ^ vswz(row);
                        s8v vfrag = *(const s8v*)&lsV[cur][row*64 + (byt >> 1)];
                        o[dt] = __builtin_amdgcn_mfma_f32_16x16x32_bf16(pa[c], vfrag, o[dt], 0,0,0);
                    }
                }
                __builtin_amdgcn_s_setprio(0);
            }
            __syncthreads();           // bar2: drains gll; publishes lsK(t+1), lsV[cur^1]
        }
        // ---- epilogue: redistribute per-q l across lane groups ----
        #pragma unroll
        for (int r=0;r<4;r++) {
            float lr = __shfl(l, (prow0 + r) + (lane & 48));
            float inv = 1.0f / lr;
            int rq = q0 + prow0 + r;
            #pragma unroll
            for (int dt=0; dt<8; dt++) {
                int d = dt*16 + l15;
                Ob[((tokbase + rq)*NH_ + h)*HD_ + d] = f2bf(o[dt][r] * inv);
            }
        }
    }
}

// ---------------- host launcher --------------------------------------------------
extern "C" void kernel_launch(void* const* d_in, const int* in_sizes, int n_in,
                              void* d_out, int out_size, void* d_ws, size_t ws_size,
                              hipStream_t stream) {
    const float* hs  = (const float*)d_in[0];
    const float* w_q = (const float*)d_in[1];
    const float* b_q = (const float*)d_in[2];
    const float* w_k = (const float*)d_in[3];
    const float* b_k = (const float*)d_in[4];
    const float* w_v = (const float*)d_in[5];
    const float* b_v = (const float*)d_in[6];
    const float* w_o = (const float*)d_in[7];
    float* out = (float*)d_out;

    char* p = (char*)d_ws;
    auto alloc = [&](size_t bytes) { char* r = p; p += (bytes + 255) & ~(size_t)255; return r; };
    unsigned short* hid_h = (unsigned short*)alloc((size_t)NTOK*HID_*2);
    unsigned short* hid_l = (unsigned short*)alloc((size_t)NTOK*HID_*2);
    unsigned short* wq_h  = (unsigned short*)alloc((size_t)NH_*HD_*HID_*2);
    unsigned short* wk_h  = (unsigned short*)alloc((size_t)NKV_*HD_*HID_*2);
    unsigned short* wk_l  = (unsigned short*)alloc((size_t)NKV_*HD_*HID_*2);
    unsigned short* wv_h  = (unsigned short*)alloc((size_t)NKV_*HD_*HID_*2);
    unsigned short* wv_l  = (unsigned short*)alloc((size_t)NKV_*HD_*HID_*2);
    unsigned short* wo_h  = (unsigned short*)alloc((size_t)HID_*NH_*HD_*2);
    unsigned short* qb = (unsigned short*)alloc((size_t)NTOK*NH_*HD_*2);
    unsigned short* kb = (unsigned short*)alloc((size_t)NTOK*NKV_*HD_*2);
    unsigned short* vb = (unsigned short*)alloc((size_t)NTOK*NKV_*HD_*2);
    unsigned short* ao = (unsigned short*)alloc((size_t)NTOK*NH_*HD_*2);
    float* ctab = (float*)alloc((size_t)S_*64*4);
    float* stab = (float*)alloc((size_t)S_*64*4);

    // conversions + rope table (1 launch)
    {
        int n8 = NTOK*HID_/8 + NH_*HD_*HID_/8 + 2*(NKV_*HD_*HID_/8) + HID_*NH_*HD_/8;
        int total = n8 + S_*64;
        prep_all<<<(total + 255)/256, 256, 0, stream>>>(
            hs, w_q, w_k, w_v, w_o, hid_h, hid_l, wq_h, wk_h, wk_l, wv_h, wv_l, wo_h,
            ctab, stab);
    }

    // fused Q + KV projections, balanced XCD swizzle: 768 blocks, one launch
    qkv_gemm<<<768, 256, 0, stream>>>(
        hid_h, hid_l, wq_h, wk_h, wk_l, wv_h, wv_l,
        b_q, b_k, b_v, qb, kb, vb, ctab, stab);

    // causal GQA attention: 512 uniform blocks x 4 waves, QBLK=64 pairs (R10)
    attn_kernel<<<B_*NH_*16, 256, 0, stream>>>(qb, kb, vb, ao);

    // output projection (no bias), XCD-swizzled, 1-pass bf16 -> fp32 d_out
    wo_gemm<<<(NTOK/128)*(HID_/128), 256, 0, stream>>>(ao, wo_h, out);
}